// Round 4
// baseline (208.489 us; speedup 1.0000x reference)
//
#include <hip/hip_runtime.h>
#include <hip/hip_fp16.h>

// HyperedgeAggregator: out[s, :] = mean over members i with segment_ids[i]==s
// of node_embeddings[node_indices[i], :].
//
// NUM_NODES=100000, EMBED_DIM=256, NUM_EDGES=16384, TOTAL=524288, seg_ids SORTED.
//
// Model (R3 post-mortem): gather is bound by per-CU outstanding-miss capacity
// (MSHR ~64) x random-gather latency (~420 cyc, L3 hit): 0.15 lines/cyc/CU.
// Only lever: fewer cache lines. Stage an fp16 copy of the table in d_ws
// (streaming convert, ~25us) -> gathered bytes 537MB -> 268MB, lines halve.
// Precision: fp16 rel err 2^-11 on N(0,1), mean of ~32 -> ~1e-3 added error,
// threshold is 2.06e-2.
//
// Plan:
//   1) convert_kernel: fp32 table -> fp16 table in d_ws (coalesced, uint4 stores)
//   2) seg_bounds_kernel: seg_start[NUM_EDGES+1] in d_ws tail
//   3) hyperedge_agg_f16_kernel: one wave per segment; 64 indices batched +
//      __shfl broadcast; 8 independent 512-B row gathers in flight.

#define EMBED_DIM 256
#define NUM_EDGES 16384
#define TOTAL_MEM 524288
#define NUM_NODES 100000

#define TAB16_BYTES ((size_t)NUM_NODES * EMBED_DIM * 2)         // 51,200,000
#define BOUNDS_BYTES ((size_t)(NUM_EDGES + 1) * sizeof(int))    // 65,540

__global__ __launch_bounds__(256) void convert_f32_to_f16_kernel(
    const float4* __restrict__ in,   // fp32 table viewed as float4 [NUM_NODES*64]
    uint4*        __restrict__ out)  // fp16 table viewed as uint4  [NUM_NODES*32]
{
    const int j = blockIdx.x * blockDim.x + threadIdx.x;  // one uint4 (8 halves)
    const int n_out = NUM_NODES * (EMBED_DIM / 8);        // 3,200,000 (exact grid)
    if (j >= n_out) return;
    float4 a = in[2 * j];
    float4 b = in[2 * j + 1];
    __half2 h0 = __floats2half2_rn(a.x, a.y);
    __half2 h1 = __floats2half2_rn(a.z, a.w);
    __half2 h2 = __floats2half2_rn(b.x, b.y);
    __half2 h3 = __floats2half2_rn(b.z, b.w);
    uint4 o;
    o.x = *reinterpret_cast<unsigned int*>(&h0);
    o.y = *reinterpret_cast<unsigned int*>(&h1);
    o.z = *reinterpret_cast<unsigned int*>(&h2);
    o.w = *reinterpret_cast<unsigned int*>(&h3);
    out[j] = o;
}

__global__ __launch_bounds__(256) void seg_bounds_kernel(
    const int* __restrict__ seg_ids,   // [TOTAL_MEM], sorted ascending
    int*       __restrict__ seg_start) // [NUM_EDGES+1]
{
    const int i = blockIdx.x * blockDim.x + threadIdx.x;
    if (i >= TOTAL_MEM) return;
    const int cur  = seg_ids[i];
    const int prev = (i == 0) ? -1 : seg_ids[i - 1];
    for (int s = prev + 1; s <= cur; ++s) seg_start[s] = i;
    if (i == TOTAL_MEM - 1) {
        for (int s = cur + 1; s <= NUM_EDGES; ++s) seg_start[s] = TOTAL_MEM;
    }
}

__global__ __launch_bounds__(256) void hyperedge_agg_f16_kernel(
    const uint2* __restrict__ tab,        // fp16 table: 64 x uint2 per row
    const int*   __restrict__ node_idx,   // [TOTAL_MEM]
    const int*   __restrict__ seg_start,  // [NUM_EDGES+1]
    float*       __restrict__ out)        // [NUM_EDGES, EMBED_DIM]
{
    const int wave = threadIdx.x >> 6;           // 4 waves per block
    const int lane = threadIdx.x & 63;
    const int seg  = blockIdx.x * 4 + wave;
    if (seg >= NUM_EDGES) return;

    const int start = seg_start[seg];
    const int end   = seg_start[seg + 1];

    float4 acc = make_float4(0.f, 0.f, 0.f, 0.f);

    int i = start;
    while (i < end) {
        const int batch = min(end - i, 64);
        const int my = (lane < batch) ? node_idx[i + lane] : 0;  // coalesced

        for (int j = 0; j < batch; j += 8) {
            const int m = min(batch - j, 8);   // wave-uniform
            uint2 v[8];
            #pragma unroll
            for (int t = 0; t < 8; ++t)
                if (t < m) {
                    const int n = __shfl(my, j + t);
                    // row = 512 B; lane reads 8 B -> 64 x 8 B coalesced
                    v[t] = tab[(size_t)n * (EMBED_DIM / 4) + lane];
                }
            #pragma unroll
            for (int t = 0; t < 8; ++t)
                if (t < m) {
                    __half2 h0 = *reinterpret_cast<__half2*>(&v[t].x);
                    __half2 h1 = *reinterpret_cast<__half2*>(&v[t].y);
                    float2 f0 = __half22float2(h0);
                    float2 f1 = __half22float2(h1);
                    acc.x += f0.x; acc.y += f0.y;
                    acc.z += f1.x; acc.w += f1.y;
                }
        }
        i += batch;
    }

    const float cnt = (end > start) ? (float)(end - start) : 1.0f;
    acc.x /= cnt; acc.y /= cnt; acc.z /= cnt; acc.w /= cnt;

    ((float4*)(out + (size_t)seg * EMBED_DIM))[lane] = acc;
}

// ---------- fp32 fallback paths ----------

__global__ __launch_bounds__(256) void hyperedge_agg_kernel(
    const float* __restrict__ emb,
    const int*   __restrict__ node_idx,
    const int*   __restrict__ seg_start,
    float*       __restrict__ out)
{
    const int wave = threadIdx.x >> 6;
    const int lane = threadIdx.x & 63;
    const int seg  = blockIdx.x * 4 + wave;
    if (seg >= NUM_EDGES) return;

    const int start = seg_start[seg];
    const int end   = seg_start[seg + 1];

    float4 acc = make_float4(0.f, 0.f, 0.f, 0.f);
    int i = start;
    while (i < end) {
        const int batch = min(end - i, 64);
        const int my = (lane < batch) ? node_idx[i + lane] : 0;
        for (int j = 0; j < batch; j += 8) {
            const int m = min(batch - j, 8);
            float4 v[8];
            #pragma unroll
            for (int t = 0; t < 8; ++t)
                if (t < m) {
                    const int n = __shfl(my, j + t);
                    v[t] = ((const float4*)(emb + (size_t)n * EMBED_DIM))[lane];
                }
            #pragma unroll
            for (int t = 0; t < 8; ++t)
                if (t < m) {
                    acc.x += v[t].x; acc.y += v[t].y;
                    acc.z += v[t].z; acc.w += v[t].w;
                }
        }
        i += batch;
    }
    const float cnt = (end > start) ? (float)(end - start) : 1.0f;
    acc.x /= cnt; acc.y /= cnt; acc.z /= cnt; acc.w /= cnt;
    ((float4*)(out + (size_t)seg * EMBED_DIM))[lane] = acc;
}

__global__ __launch_bounds__(256) void hyperedge_agg_bsearch_kernel(
    const float* __restrict__ emb,
    const int*   __restrict__ node_idx,
    const int*   __restrict__ seg_ids,
    float*       __restrict__ out)
{
    const int wave = threadIdx.x >> 6;
    const int lane = threadIdx.x & 63;
    const int seg  = blockIdx.x * 4 + wave;
    if (seg >= NUM_EDGES) return;

    int lo = 0, hi = TOTAL_MEM;
    while (lo < hi) {
        int mid = (lo + hi) >> 1;
        if (seg_ids[mid] < seg) lo = mid + 1; else hi = mid;
    }
    const int start = lo;
    hi = TOTAL_MEM;
    while (lo < hi) {
        int mid = (lo + hi) >> 1;
        if (seg_ids[mid] < seg + 1) lo = mid + 1; else hi = mid;
    }
    const int end = lo;

    float4 acc = make_float4(0.f, 0.f, 0.f, 0.f);
    for (int i = start; i < end; ++i) {
        const int n = node_idx[i];
        float4 v = ((const float4*)(emb + (size_t)n * EMBED_DIM))[lane];
        acc.x += v.x; acc.y += v.y; acc.z += v.z; acc.w += v.w;
    }
    const float cnt = (end > start) ? (float)(end - start) : 1.0f;
    acc.x /= cnt; acc.y /= cnt; acc.z /= cnt; acc.w /= cnt;
    ((float4*)(out + (size_t)seg * EMBED_DIM))[lane] = acc;
}

extern "C" void kernel_launch(void* const* d_in, const int* in_sizes, int n_in,
                              void* d_out, int out_size, void* d_ws, size_t ws_size,
                              hipStream_t stream) {
    const float* emb      = (const float*)d_in[0];
    const int*   node_idx = (const int*)d_in[1];
    const int*   seg_ids  = (const int*)d_in[2];
    float*       out      = (float*)d_out;

    if (ws_size >= TAB16_BYTES + BOUNDS_BYTES) {
        // Layout: [fp16 table | seg_start]
        uint4* tab16     = (uint4*)d_ws;
        int*   seg_start = (int*)((char*)d_ws + TAB16_BYTES);

        const int n_out4 = NUM_NODES * (EMBED_DIM / 8);  // 3,200,000 uint4
        convert_f32_to_f16_kernel<<<(n_out4 + 255) / 256, 256, 0, stream>>>(
            (const float4*)emb, tab16);
        seg_bounds_kernel<<<(TOTAL_MEM + 255) / 256, 256, 0, stream>>>(seg_ids, seg_start);
        hyperedge_agg_f16_kernel<<<NUM_EDGES / 4, 256, 0, stream>>>(
            (const uint2*)tab16, node_idx, seg_start, out);
    } else if (ws_size >= BOUNDS_BYTES) {
        int* seg_start = (int*)d_ws;
        seg_bounds_kernel<<<(TOTAL_MEM + 255) / 256, 256, 0, stream>>>(seg_ids, seg_start);
        hyperedge_agg_kernel<<<NUM_EDGES / 4, 256, 0, stream>>>(emb, node_idx, seg_start, out);
    } else {
        hyperedge_agg_bsearch_kernel<<<NUM_EDGES / 4, 256, 0, stream>>>(emb, node_idx, seg_ids, out);
    }
}